// Round 1
// baseline (245.235 us; speedup 1.0000x reference)
//
#include <hip/hip_runtime.h>

// DynamicRouting (capsule routing), MI355X.
// votes: [B=128, I=2048, O=32, P=4] fp32. activations_in unused by reference.
// b_ij^(t)[b,i,o] = sum_{tau<t} dot(votes[b,i,o,:], v^tau[b,o,:]) -> never materialize b_ij.
// 3 passes over votes (memory-bound); tiny squash kernel between passes.

#define BATCH 128
#define IC 2048
#define OC 32
#define POSE 4
#define REPS 1e-7f
#define CHUNKS 16
#define CHUNK_I (IC / CHUNKS)      // 128
#define BLOCK_T 256
#define GROUPS (BLOCK_T / 32)      // 8 o-groups per block

__global__ __launch_bounds__(BLOCK_T) void routing_accum(
    const float4* __restrict__ votes,   // [B*IC*OC] float4 (pose vector per element)
    const float4* __restrict__ v_hist,  // [3][B*OC] float4
    float* __restrict__ s_out,          // [B*OC*4] floats, pre-zeroed, atomic accum
    int t)
{
    const int blk   = blockIdx.x;
    const int b     = blk >> 4;            // / CHUNKS
    const int chunk = blk & (CHUNKS - 1);
    const int o     = threadIdx.x & 31;    // lane's fixed out-capsule
    const int g     = threadIdx.x >> 5;    // o-group index within block (0..7)

    // v history for this (b, o): at most 2 prior iterations, kept in registers
    float4 vh0 = make_float4(0.f, 0.f, 0.f, 0.f);
    float4 vh1 = make_float4(0.f, 0.f, 0.f, 0.f);
    if (t >= 1) vh0 = v_hist[0 * BATCH * OC + b * OC + o];
    if (t >= 2) vh1 = v_hist[1 * BATCH * OC + b * OC + o];

    float4 s_acc = make_float4(0.f, 0.f, 0.f, 0.f);

    const float4* vb = votes + (size_t)b * IC * OC;
    const int i0 = chunk * CHUNK_I;

    for (int step = 0; step < CHUNK_I / GROUPS; ++step) {
        const int i = i0 + step * GROUPS + g;
        const float4 vt = vb[(size_t)i * OC + o];   // wave reads 1 KiB contiguous

        float logit = 0.f;
        if (t >= 1) logit += vt.x*vh0.x + vt.y*vh0.y + vt.z*vh0.z + vt.w*vh0.w;
        if (t >= 2) logit += vt.x*vh1.x + vt.y*vh1.y + vt.z*vh1.z + vt.w*vh1.w;

        // softmax over the 32-lane o-group (masks<32 keep bit5 -> stay in group)
        float m = logit;
        #pragma unroll
        for (int d = 16; d >= 1; d >>= 1) m = fmaxf(m, __shfl_xor(m, d));
        float e = __expf(logit - m);
        float ssum = e;
        #pragma unroll
        for (int d = 16; d >= 1; d >>= 1) ssum += __shfl_xor(ssum, d);
        const float c = e / ssum;

        s_acc.x += c * vt.x;
        s_acc.y += c * vt.y;
        s_acc.z += c * vt.z;
        s_acc.w += c * vt.w;
    }

    __shared__ float4 lds_s[GROUPS * 32];
    lds_s[g * 32 + o] = s_acc;
    __syncthreads();

    if (threadIdx.x < 32) {
        float4 tot = lds_s[o];
        #pragma unroll
        for (int gg = 1; gg < GROUPS; ++gg) {
            const float4 x = lds_s[gg * 32 + o];
            tot.x += x.x; tot.y += x.y; tot.z += x.z; tot.w += x.w;
        }
        float* dst = s_out + ((size_t)b * OC + o) * 4;
        atomicAdd(dst + 0, tot.x);   // 16 chunk-blocks contend per address
        atomicAdd(dst + 1, tot.y);
        atomicAdd(dst + 2, tot.z);
        atomicAdd(dst + 3, tot.w);
    }
}

__global__ void routing_squash(
    const float4* __restrict__ s_in,   // [B*OC]
    float4* __restrict__ v_out,        // v_hist[t]
    float* __restrict__ out,           // d_out (last iter) or nullptr
    int is_last)
{
    const int idx = blockIdx.x * blockDim.x + threadIdx.x;
    if (idx >= BATCH * OC) return;
    const float4 s = s_in[idx];
    // s_norm = sqrt(sum s^2 + eps); scale = n2/(1+n2); v = scale * s / s_norm
    const float n2 = s.x*s.x + s.y*s.y + s.z*s.z + s.w*s.w + REPS;
    const float inv_norm = rsqrtf(n2);
    const float f = n2 / (1.f + n2) * inv_norm;
    const float4 v = make_float4(f*s.x, f*s.y, f*s.z, f*s.w);
    v_out[idx] = v;
    if (is_last) {
        ((float4*)out)[idx] = v;                                      // poses_out [B,O,P]
        const float a = sqrtf(v.x*v.x + v.y*v.y + v.z*v.z + v.w*v.w + REPS);
        out[BATCH * OC * POSE + idx] = a;                             // activations_out [B,O,1]
    }
}

extern "C" void kernel_launch(void* const* d_in, const int* in_sizes, int n_in,
                              void* d_out, int out_size, void* d_ws, size_t ws_size,
                              hipStream_t stream) {
    const float4* votes = (const float4*)d_in[0];
    // d_in[1] (activations_in) is unused by the reference.

    float* ws = (float*)d_ws;
    float4* v_hist = (float4*)ws;                      // 3 * B*OC float4
    float* s_all   = ws + (size_t)3 * BATCH * OC * 4;  // 3 * B*OC*4 floats

    // ws is poisoned 0xAA before every timed launch -> zero the s accumulators.
    hipMemsetAsync(s_all, 0, (size_t)3 * BATCH * OC * 4 * sizeof(float), stream);

    for (int t = 0; t < 3; ++t) {
        float* s_t = s_all + (size_t)t * BATCH * OC * 4;
        routing_accum<<<BATCH * CHUNKS, BLOCK_T, 0, stream>>>(
            votes, v_hist, s_t, t);
        routing_squash<<<(BATCH * OC + 255) / 256, 256, 0, stream>>>(
            (const float4*)s_t, v_hist + (size_t)t * BATCH * OC,
            (t == 2) ? (float*)d_out : nullptr, (t == 2) ? 1 : 0);
    }
}

// Round 2
// 239.336 us; speedup vs baseline: 1.0246x; 1.0246x over previous
//
#include <hip/hip_runtime.h>

// DynamicRouting (capsule routing), MI355X / gfx950.
// votes: [B=128, I=2048, O=32, P=4] fp32 (128 MiB). activations_in unused.
// b_ij^(t)[b,i,o] = sum_{tau<t} dot(votes[b,i,o,:], v^tau[b,o,:]) -> b_ij never materialized.
//
// R1 changes vs R0 (245 us):
//  - iter 0 special-cased: softmax(0) == 1/32 uniform -> pure streaming mean (no shuffles/exp/div)
//  - iters 1-2: max-subtraction tree dropped (logits bounded ~|8|, exp safe in fp32)
//  - exact fp32 divide -> v_rcp_f32 (1 instr vs ~12)
//  - 2 independent i's per thread-step: two softmax chains interleave to hide swizzle latency

#define BATCH 128
#define IC 2048
#define OC 32
#define POSE 4
#define REPS 1e-7f
#define CHUNKS 16
#define CHUNK_I (IC / CHUNKS)      // 128 input capsules per block
#define BLOCK_T 256
#define GROUPS (BLOCK_T / 32)      // 8 o-groups per block
#define STEPS (CHUNK_I / (GROUPS * 2))  // 8 steps, 2 i's per thread per step

__device__ __forceinline__ float dot4(const float4 a, const float4 b) {
    return a.x*b.x + a.y*b.y + a.z*b.z + a.w*b.w;
}

template <int T>
__global__ __launch_bounds__(BLOCK_T) void routing_accum(
    const float4* __restrict__ votes,   // [B*IC*OC] float4 (pose vec per (b,i,o))
    const float4* __restrict__ v_hist,  // [3][B*OC] float4
    float* __restrict__ s_out)          // [B*OC*4], pre-zeroed, atomic accum
{
    const int blk   = blockIdx.x;
    const int b     = blk >> 4;            // / CHUNKS
    const int chunk = blk & (CHUNKS - 1);
    const int o     = threadIdx.x & 31;    // lane's fixed out-capsule
    const int g     = threadIdx.x >> 5;    // o-group index within block (0..7)

    float4 vh0 = make_float4(0.f, 0.f, 0.f, 0.f);
    float4 vh1 = make_float4(0.f, 0.f, 0.f, 0.f);
    if (T >= 1) vh0 = v_hist[0 * BATCH * OC + b * OC + o];
    if (T >= 2) vh1 = v_hist[1 * BATCH * OC + b * OC + o];

    float4 s_acc = make_float4(0.f, 0.f, 0.f, 0.f);

    const float4* vb = votes + (size_t)b * IC * OC;
    const int i0 = chunk * CHUNK_I;

    #pragma unroll
    for (int step = 0; step < STEPS; ++step) {
        const int ia = i0 + step * (GROUPS * 2) + g;  // wave: 2 contiguous 512B rows
        const int ib = ia + GROUPS;
        const float4 va = vb[(size_t)ia * OC + o];
        const float4 vc = vb[(size_t)ib * OC + o];

        if (T == 0) {
            // softmax(0) == 1/32 uniform; scale applied at block-reduce
            s_acc.x += va.x + vc.x;
            s_acc.y += va.y + vc.y;
            s_acc.z += va.z + vc.z;
            s_acc.w += va.w + vc.w;
        } else {
            float la = dot4(va, vh0);
            float lb = dot4(vc, vh0);
            if (T >= 2) { la += dot4(va, vh1); lb += dot4(vc, vh1); }

            // no max-subtraction: |logit| <~ 8 (|v|<1, votes ~ N(0,1)) -> exp safe in fp32
            float ea = __expf(la);
            float eb = __expf(lb);
            float sa = ea, sb = eb;
            // butterfly sum over the 32-lane o-group; two independent chains interleave
            #pragma unroll
            for (int d = 16; d >= 1; d >>= 1) {
                sa += __shfl_xor(sa, d);
                sb += __shfl_xor(sb, d);
            }
            const float ca = ea * __builtin_amdgcn_rcpf(sa);
            const float cb = eb * __builtin_amdgcn_rcpf(sb);

            s_acc.x += ca * va.x + cb * vc.x;
            s_acc.y += ca * va.y + cb * vc.y;
            s_acc.z += ca * va.z + cb * vc.z;
            s_acc.w += ca * va.w + cb * vc.w;
        }
    }

    __shared__ float4 lds_s[GROUPS * 32];
    lds_s[g * 32 + o] = s_acc;
    __syncthreads();

    if (threadIdx.x < 32) {
        float4 tot = lds_s[o];
        #pragma unroll
        for (int gg = 1; gg < GROUPS; ++gg) {
            const float4 x = lds_s[gg * 32 + o];
            tot.x += x.x; tot.y += x.y; tot.z += x.z; tot.w += x.w;
        }
        if (T == 0) {
            const float inv = 1.f / 32.f;   // uniform softmax weight
            tot.x *= inv; tot.y *= inv; tot.z *= inv; tot.w *= inv;
        }
        float* dst = s_out + ((size_t)b * OC + o) * 4;
        atomicAdd(dst + 0, tot.x);   // 16 chunk-blocks contend per address
        atomicAdd(dst + 1, tot.y);
        atomicAdd(dst + 2, tot.z);
        atomicAdd(dst + 3, tot.w);
    }
}

__global__ void routing_squash(
    const float4* __restrict__ s_in,   // [B*OC]
    float4* __restrict__ v_out,        // v_hist[t]
    float* __restrict__ out,           // d_out (last iter) or nullptr
    int is_last)
{
    const int idx = blockIdx.x * blockDim.x + threadIdx.x;
    if (idx >= BATCH * OC) return;
    const float4 s = s_in[idx];
    const float n2 = s.x*s.x + s.y*s.y + s.z*s.z + s.w*s.w + REPS;
    const float inv_norm = rsqrtf(n2);
    const float f = n2 / (1.f + n2) * inv_norm;
    const float4 v = make_float4(f*s.x, f*s.y, f*s.z, f*s.w);
    v_out[idx] = v;
    if (is_last) {
        ((float4*)out)[idx] = v;                                      // poses_out [B,O,P]
        const float a = sqrtf(v.x*v.x + v.y*v.y + v.z*v.z + v.w*v.w + REPS);
        out[BATCH * OC * POSE + idx] = a;                             // activations_out [B,O,1]
    }
}

extern "C" void kernel_launch(void* const* d_in, const int* in_sizes, int n_in,
                              void* d_out, int out_size, void* d_ws, size_t ws_size,
                              hipStream_t stream) {
    const float4* votes = (const float4*)d_in[0];
    // d_in[1] (activations_in) unused by the reference.

    float* ws = (float*)d_ws;
    float4* v_hist = (float4*)ws;                      // 3 * B*OC float4
    float* s_all   = ws + (size_t)3 * BATCH * OC * 4;  // 3 * B*OC*4 floats

    // ws is poisoned 0xAA before every timed launch -> zero the s accumulators.
    hipMemsetAsync(s_all, 0, (size_t)3 * BATCH * OC * 4 * sizeof(float), stream);

    for (int t = 0; t < 3; ++t) {
        float* s_t = s_all + (size_t)t * BATCH * OC * 4;
        if (t == 0)      routing_accum<0><<<BATCH * CHUNKS, BLOCK_T, 0, stream>>>(votes, v_hist, s_t);
        else if (t == 1) routing_accum<1><<<BATCH * CHUNKS, BLOCK_T, 0, stream>>>(votes, v_hist, s_t);
        else             routing_accum<2><<<BATCH * CHUNKS, BLOCK_T, 0, stream>>>(votes, v_hist, s_t);
        routing_squash<<<(BATCH * OC + 255) / 256, 256, 0, stream>>>(
            (const float4*)s_t, v_hist + (size_t)t * BATCH * OC,
            (t == 2) ? (float*)d_out : nullptr, (t == 2) ? 1 : 0);
    }
}

// Round 3
// 236.683 us; speedup vs baseline: 1.0361x; 1.0112x over previous
//
#include <hip/hip_runtime.h>

// DynamicRouting (capsule routing), MI355X / gfx950.
// votes: [B=128, I=2048, O=32, P=4] fp32 (128 MiB). activations_in unused.
// b_ij^(t)[b,i,o] = sum_{tau<t} dot(votes[b,i,o,:], v^tau[b,o,:]) -> b_ij never materialized.
//
// R2 changes vs R1 (239 us):
//  - squash fused into accum head: v_{t-1}, v_{t-2} recomputed per-thread from stored s sums
//    (removes 3 tiny squash launches; graph 7 -> 5 nodes)
//  - 4 independent i's per thread-step: 4 softmax shuffle chains interleave
//  - single finalize kernel writes poses_out + activations_out from s_2

#define BATCH 128
#define IC 2048
#define OC 32
#define POSE 4
#define REPS 1e-7f
#define CHUNKS 16
#define CHUNK_I (IC / CHUNKS)          // 128 input capsules per block
#define BLOCK_T 256
#define GROUPS (BLOCK_T / 32)          // 8 o-groups per block
#define ILP 4
#define STEPS (CHUNK_I / (GROUPS * ILP))  // 4 steps, 4 i's per thread per step

__device__ __forceinline__ float dot4(const float4 a, const float4 b) {
    return a.x*b.x + a.y*b.y + a.z*b.z + a.w*b.w;
}

// squash: v = (n2/(1+n2)) * s / sqrt(n2),  n2 = |s|^2 + eps
__device__ __forceinline__ float4 squash4(const float4 s) {
    const float n2 = s.x*s.x + s.y*s.y + s.z*s.z + s.w*s.w + REPS;
    const float f = n2 / (1.f + n2) * rsqrtf(n2);
    return make_float4(f*s.x, f*s.y, f*s.z, f*s.w);
}

template <int T>
__global__ __launch_bounds__(BLOCK_T) void routing_accum(
    const float4* __restrict__ votes,   // [B*IC*OC] float4 (pose vec per (b,i,o))
    const float4* __restrict__ s_all,   // [3][B*OC] float4 (atomic-accumulated sums)
    float* __restrict__ s_out)          // [B*OC*4] floats, pre-zeroed, atomic accum
{
    const int blk   = blockIdx.x;
    const int b     = blk >> 4;            // / CHUNKS
    const int chunk = blk & (CHUNKS - 1);
    const int o     = threadIdx.x & 31;    // lane's fixed out-capsule
    const int g     = threadIdx.x >> 5;    // o-group index within block (0..7)

    // v history for this (b,o): recomputed inline from completed s sums (squash is ~10 VALU)
    float4 vh0 = make_float4(0.f, 0.f, 0.f, 0.f);
    float4 vh1 = make_float4(0.f, 0.f, 0.f, 0.f);
    if (T >= 1) vh0 = squash4(s_all[0 * BATCH * OC + b * OC + o]);
    if (T >= 2) vh1 = squash4(s_all[1 * BATCH * OC + b * OC + o]);

    float4 s_acc = make_float4(0.f, 0.f, 0.f, 0.f);

    const float4* vb = votes + (size_t)b * IC * OC;
    const int i0 = chunk * CHUNK_I;

    #pragma unroll
    for (int step = 0; step < STEPS; ++step) {
        const int ia = i0 + step * (GROUPS * ILP) + g;
        float4 v0 = vb[(size_t)(ia + 0 * GROUPS) * OC + o];  // wave: 1 KiB contiguous each
        float4 v1 = vb[(size_t)(ia + 1 * GROUPS) * OC + o];
        float4 v2 = vb[(size_t)(ia + 2 * GROUPS) * OC + o];
        float4 v3 = vb[(size_t)(ia + 3 * GROUPS) * OC + o];

        if (T == 0) {
            // softmax(0) == 1/32 uniform; scale applied at block-reduce
            s_acc.x += (v0.x + v1.x) + (v2.x + v3.x);
            s_acc.y += (v0.y + v1.y) + (v2.y + v3.y);
            s_acc.z += (v0.z + v1.z) + (v2.z + v3.z);
            s_acc.w += (v0.w + v1.w) + (v2.w + v3.w);
        } else {
            float l0 = dot4(v0, vh0);
            float l1 = dot4(v1, vh0);
            float l2 = dot4(v2, vh0);
            float l3 = dot4(v3, vh0);
            if (T >= 2) {
                l0 += dot4(v0, vh1); l1 += dot4(v1, vh1);
                l2 += dot4(v2, vh1); l3 += dot4(v3, vh1);
            }
            // no max-subtraction: |logit| <~ 8 (|v|<1, votes ~ N(0,1)) -> fp32 exp safe
            float e0 = __expf(l0), e1 = __expf(l1), e2 = __expf(l2), e3 = __expf(l3);
            float t0 = e0, t1 = e1, t2 = e2, t3 = e3;
            // butterfly sums over the 32-lane o-group; 4 independent chains interleave
            #pragma unroll
            for (int d = 16; d >= 1; d >>= 1) {
                t0 += __shfl_xor(t0, d);
                t1 += __shfl_xor(t1, d);
                t2 += __shfl_xor(t2, d);
                t3 += __shfl_xor(t3, d);
            }
            const float c0 = e0 * __builtin_amdgcn_rcpf(t0);
            const float c1 = e1 * __builtin_amdgcn_rcpf(t1);
            const float c2 = e2 * __builtin_amdgcn_rcpf(t2);
            const float c3 = e3 * __builtin_amdgcn_rcpf(t3);

            s_acc.x += c0*v0.x + c1*v1.x + c2*v2.x + c3*v3.x;
            s_acc.y += c0*v0.y + c1*v1.y + c2*v2.y + c3*v3.y;
            s_acc.z += c0*v0.z + c1*v1.z + c2*v2.z + c3*v3.z;
            s_acc.w += c0*v0.w + c1*v1.w + c2*v2.w + c3*v3.w;
        }
    }

    __shared__ float4 lds_s[GROUPS * 32];
    lds_s[g * 32 + o] = s_acc;
    __syncthreads();

    if (threadIdx.x < 32) {
        float4 tot = lds_s[o];
        #pragma unroll
        for (int gg = 1; gg < GROUPS; ++gg) {
            const float4 x = lds_s[gg * 32 + o];
            tot.x += x.x; tot.y += x.y; tot.z += x.z; tot.w += x.w;
        }
        if (T == 0) {
            const float inv = 1.f / 32.f;   // uniform softmax weight
            tot.x *= inv; tot.y *= inv; tot.z *= inv; tot.w *= inv;
        }
        float* dst = s_out + ((size_t)b * OC + o) * 4;
        atomicAdd(dst + 0, tot.x);   // 16 chunk-blocks contend per address
        atomicAdd(dst + 1, tot.y);
        atomicAdd(dst + 2, tot.z);
        atomicAdd(dst + 3, tot.w);
    }
}

__global__ void routing_finalize(
    const float4* __restrict__ s2,     // [B*OC] completed iteration-2 sums
    float* __restrict__ out)           // d_out: poses [B,O,P] then activations [B,O,1]
{
    const int idx = blockIdx.x * blockDim.x + threadIdx.x;
    if (idx >= BATCH * OC) return;
    const float4 v = squash4(s2[idx]);
    ((float4*)out)[idx] = v;                                       // poses_out
    const float a = sqrtf(v.x*v.x + v.y*v.y + v.z*v.z + v.w*v.w + REPS);
    out[BATCH * OC * POSE + idx] = a;                              // activations_out
}

extern "C" void kernel_launch(void* const* d_in, const int* in_sizes, int n_in,
                              void* d_out, int out_size, void* d_ws, size_t ws_size,
                              hipStream_t stream) {
    const float4* votes = (const float4*)d_in[0];
    // d_in[1] (activations_in) unused by the reference.

    float* s_all = (float*)d_ws;                       // 3 * B*OC*4 floats = 48 KiB

    // ws is poisoned 0xAA before every timed launch -> zero the s accumulators.
    hipMemsetAsync(s_all, 0, (size_t)3 * BATCH * OC * 4 * sizeof(float), stream);

    const float4* s_all4 = (const float4*)s_all;
    routing_accum<0><<<BATCH * CHUNKS, BLOCK_T, 0, stream>>>(
        votes, s_all4, s_all + 0 * BATCH * OC * 4);
    routing_accum<1><<<BATCH * CHUNKS, BLOCK_T, 0, stream>>>(
        votes, s_all4, s_all + 1 * BATCH * OC * 4);
    routing_accum<2><<<BATCH * CHUNKS, BLOCK_T, 0, stream>>>(
        votes, s_all4, s_all + 2 * BATCH * OC * 4);
    routing_finalize<<<(BATCH * OC + 255) / 256, 256, 0, stream>>>(
        s_all4 + 2 * BATCH * OC, (float*)d_out);
}